// Round 1
// baseline (697.030 us; speedup 1.0000x reference)
//
#include <hip/hip_runtime.h>
#include <math.h>

#define B_DIM 256
#define P_DIM 4
#define N_DIM 1024
#define D_DIM 512
#define NV (P_DIM + N_DIM)   // 1028 similarity entries per row
#define INV_TEMP 10.0f       // 1 / 0.1
#define POS_W 0.3f
#define EPS_C 1e-8f

__device__ __forceinline__ float wave_sum_f(float v) {
#pragma unroll
  for (int m = 1; m < 64; m <<= 1) v += __shfl_xor(v, m, 64);
  return v;
}

__device__ __forceinline__ float wave_max_f(float v) {
#pragma unroll
  for (int m = 1; m < 64; m <<= 1) v = fmaxf(v, __shfl_xor(v, m, 64));
  return v;
}

__device__ __forceinline__ int wave_sum_i(int v) {
#pragma unroll
  for (int m = 1; m < 64; m <<= 1) v += __shfl_xor(v, m, 64);
  return v;
}

__device__ __forceinline__ float dot4(float4 a, float4 b) {
  return a.x * b.x + a.y * b.y + a.z * b.z + a.w * b.w;
}

// One block per batch row. 256 threads = 4 waves.
// Phase 1: 1028 cosine sims -> LDS. Phase 2 (wave 0): softmax + rank-count.
__global__ __launch_bounds__(256) void rr_row_kernel(
    const float* __restrict__ anchor, const float* __restrict__ positives,
    const float* __restrict__ negatives, float* __restrict__ partials) {
  const int b = blockIdx.x;
  const int lane = threadIdx.x & 63;
  const int wave = threadIdx.x >> 6;

  __shared__ float sims[NV];

  // Anchor row: lane holds 8 floats as two coalesced float4 loads.
  const float4* arow = (const float4*)(anchor + (size_t)b * D_DIM);
  const float4 a0 = arow[lane];
  const float4 a1 = arow[lane + 64];
  float asq = dot4(a0, a0) + dot4(a1, a1);
  asq = wave_sum_f(asq);               // each wave redundantly reduces; same result
  const float anorm = sqrtf(asq);

  const float* posrow = positives + (size_t)b * P_DIM * D_DIM;
  const float* negrow = negatives + (size_t)b * N_DIM * D_DIM;

  // Each wave handles 4 consecutive vectors per iteration -> 8 outstanding
  // float4 loads per lane before any reduction (latency hiding).
  for (int v0 = wave * 4; v0 < NV; v0 += 16) {
    float4 bv[4][2];
#pragma unroll
    for (int i = 0; i < 4; ++i) {
      const int v = v0 + i;
      if (v < NV) {
        const float* src = (v < P_DIM) ? (posrow + (size_t)v * D_DIM)
                                       : (negrow + (size_t)(v - P_DIM) * D_DIM);
        const float4* p = (const float4*)src;
        bv[i][0] = p[lane];
        bv[i][1] = p[lane + 64];
      }
    }
#pragma unroll
    for (int i = 0; i < 4; ++i) {
      const int v = v0 + i;
      if (v < NV) {
        const float4 b0 = bv[i][0];
        const float4 b1 = bv[i][1];
        float d  = dot4(a0, b0) + dot4(a1, b1);
        float bq = dot4(b0, b0) + dot4(b1, b1);
        d  = wave_sum_f(d);
        bq = wave_sum_f(bq);
        if (lane == 0) {
          const float den = fmaxf(anorm * sqrtf(bq), EPS_C);
          sims[v] = d / den;
        }
      }
    }
  }
  __syncthreads();

  if (wave == 0) {
    // max of sims/T
    float m = -3.4e38f;
    for (int v = lane; v < NV; v += 64) m = fmaxf(m, sims[v] * INV_TEMP);
    m = wave_max_f(m);
    // softmax denominator
    float Z = 0.0f;
    for (int v = lane; v < NV; v += 64) Z += expf(sims[v] * INV_TEMP - m);
    Z = wave_sum_f(Z);
    // ranks of the 4 positives (indices 0..3): stable-argsort semantics:
    // rank_k = #{i: s_i > s_k} + #{i < k: s_i == s_k}
    const float sp0 = sims[0], sp1 = sims[1], sp2 = sims[2], sp3 = sims[3];
    int c0 = 0, c1 = 0, c2 = 0, c3 = 0;
    for (int v = lane; v < NV; v += 64) {
      const float s = sims[v];
      c0 += (s > sp0);
      c1 += (s > sp1) || (s == sp1 && v < 1);
      c2 += (s > sp2) || (s == sp2 && v < 2);
      c3 += (s > sp3) || (s == sp3 && v < 3);
    }
    c0 = wave_sum_i(c0);
    c1 = wave_sum_i(c1);
    c2 = wave_sum_i(c2);
    c3 = wave_sum_i(c3);
    if (lane == 0) {
      const float invZ = 1.0f / Z;
      const float p0 = expf(sp0 * INV_TEMP - m) * invZ;
      const float p1 = expf(sp1 * INV_TEMP - m) * invZ;
      const float p2 = expf(sp2 * INV_TEMP - m) * invZ;
      const float p3 = expf(sp3 * INV_TEMP - m) * invZ;
      const float err = p0 / (float)(c0 + 1) + p1 / (float)(c1 + 1) +
                        p2 / (float)(c2 + 1) + p3 / (float)(c3 + 1);
      partials[b] = err;                          // expected RR for this row
      partials[B_DIM + b] = sp0 + sp1 + sp2 + sp3; // sum of pos sims
    }
  }
}

__global__ __launch_bounds__(256) void rr_finalize_kernel(
    const float* __restrict__ partials, float* __restrict__ out) {
  const int t = threadIdx.x;
  const int lane = t & 63;
  const int wave = t >> 6;
  float rr = partials[t];
  float ps = partials[B_DIM + t];
  rr = wave_sum_f(rr);
  ps = wave_sum_f(ps);
  __shared__ float srr[4], sps[4];
  if (lane == 0) { srr[wave] = rr; sps[wave] = ps; }
  __syncthreads();
  if (t == 0) {
    const float SRR = srr[0] + srr[1] + srr[2] + srr[3];
    const float SPS = sps[0] + sps[1] + sps[2] + sps[3];
    const float loss =
        -(SRR / (float)B_DIM) +
        POS_W * (1.0f - SPS / (float)(B_DIM * P_DIM));
    out[0] = loss;
  }
}

extern "C" void kernel_launch(void* const* d_in, const int* in_sizes, int n_in,
                              void* d_out, int out_size, void* d_ws, size_t ws_size,
                              hipStream_t stream) {
  const float* anchor = (const float*)d_in[0];
  const float* positives = (const float*)d_in[1];
  const float* negatives = (const float*)d_in[2];
  float* partials = (float*)d_ws;  // 2*B_DIM floats, fully overwritten each launch
  float* out = (float*)d_out;

  rr_row_kernel<<<B_DIM, 256, 0, stream>>>(anchor, positives, negatives, partials);
  rr_finalize_kernel<<<1, 256, 0, stream>>>(partials, out);
}

// Round 2
// 679.005 us; speedup vs baseline: 1.0265x; 1.0265x over previous
//
#include <hip/hip_runtime.h>
#include <math.h>

#define B_DIM 256
#define P_DIM 4
#define N_DIM 1024
#define D_DIM 512
#define NV (P_DIM + N_DIM)   // 1028 similarity entries per row; NV % 64 == 4
#define INV_TEMP 10.0f       // 1 / 0.1
#define POS_W 0.3f
#define EPS_C 1e-8f

__device__ __forceinline__ float wave_sum_f(float v) {
#pragma unroll
  for (int m = 1; m < 64; m <<= 1) v += __shfl_xor(v, m, 64);
  return v;
}

__device__ __forceinline__ float wave_max_f(float v) {
#pragma unroll
  for (int m = 1; m < 64; m <<= 1) v = fmaxf(v, __shfl_xor(v, m, 64));
  return v;
}

__device__ __forceinline__ int wave_sum_i(int v) {
#pragma unroll
  for (int m = 1; m < 64; m <<= 1) v += __shfl_xor(v, m, 64);
  return v;
}

__device__ __forceinline__ float dot4(float4 a, float4 b) {
  return a.x * b.x + a.y * b.y + a.z * b.z + a.w * b.w;
}

// One block per batch row. 1024 threads = 16 waves/CU (vs 4 in round 1 —
// occupancy was the latency-hiding bottleneck).
// Phase 1: 1028 cosine sims -> LDS. Phase 2 (wave 0): softmax + rank-count.
// NV = 1028 = 4 (mod 64) and waves stride 64 vectors in groups of 4, so every
// group of 4 vectors is fully in-bounds: phase 1 is guard-free.
__global__ __launch_bounds__(1024) void rr_row_kernel(
    const float* __restrict__ anchor, const float* __restrict__ positives,
    const float* __restrict__ negatives, float* __restrict__ partials) {
  const int b = blockIdx.x;
  const int lane = threadIdx.x & 63;
  const int wave = threadIdx.x >> 6;

  __shared__ float sims[NV];

  // Anchor row: lane holds 8 floats as two coalesced float4 loads.
  const float4* arow = (const float4*)(anchor + (size_t)b * D_DIM);
  const float4 a0 = arow[lane];
  const float4 a1 = arow[lane + 64];
  float asq = dot4(a0, a0) + dot4(a1, a1);
  asq = wave_sum_f(asq);               // each wave redundantly reduces; same result
  const float anorm = sqrtf(asq);

  const float* posrow = positives + (size_t)b * P_DIM * D_DIM;
  const float* negrow = negatives + (size_t)b * N_DIM * D_DIM;

  // Each wave: 4 consecutive vectors per iteration -> 8 outstanding float4
  // loads per lane before any reduction; 8 independent shuffle chains of ILP.
  for (int v0 = wave * 4; v0 < NV; v0 += 64) {
    float4 bv[4][2];
#pragma unroll
    for (int i = 0; i < 4; ++i) {
      const int v = v0 + i;
      const float* src = (v < P_DIM) ? (posrow + (size_t)v * D_DIM)
                                     : (negrow + (size_t)(v - P_DIM) * D_DIM);
      const float4* p = (const float4*)src;
      bv[i][0] = p[lane];
      bv[i][1] = p[lane + 64];
    }
    float d[4], bq[4];
#pragma unroll
    for (int i = 0; i < 4; ++i) {
      d[i]  = dot4(a0, bv[i][0]) + dot4(a1, bv[i][1]);
      bq[i] = dot4(bv[i][0], bv[i][0]) + dot4(bv[i][1], bv[i][1]);
    }
#pragma unroll
    for (int i = 0; i < 4; ++i) {
      d[i]  = wave_sum_f(d[i]);
      bq[i] = wave_sum_f(bq[i]);
    }
    if (lane == 0) {
#pragma unroll
      for (int i = 0; i < 4; ++i) {
        const float den = fmaxf(anorm * sqrtf(bq[i]), EPS_C);
        sims[v0 + i] = d[i] / den;
      }
    }
  }
  __syncthreads();

  if (wave == 0) {
    // max of sims/T
    float m = -3.4e38f;
    for (int v = lane; v < NV; v += 64) m = fmaxf(m, sims[v] * INV_TEMP);
    m = wave_max_f(m);
    // softmax denominator
    float Z = 0.0f;
    for (int v = lane; v < NV; v += 64) Z += expf(sims[v] * INV_TEMP - m);
    Z = wave_sum_f(Z);
    // ranks of the 4 positives (indices 0..3), stable-argsort semantics:
    // rank_k = #{i: s_i > s_k} + #{i < k: s_i == s_k}
    const float sp0 = sims[0], sp1 = sims[1], sp2 = sims[2], sp3 = sims[3];
    int c0 = 0, c1 = 0, c2 = 0, c3 = 0;
    for (int v = lane; v < NV; v += 64) {
      const float s = sims[v];
      c0 += (s > sp0);
      c1 += (s > sp1) || (s == sp1 && v < 1);
      c2 += (s > sp2) || (s == sp2 && v < 2);
      c3 += (s > sp3) || (s == sp3 && v < 3);
    }
    c0 = wave_sum_i(c0);
    c1 = wave_sum_i(c1);
    c2 = wave_sum_i(c2);
    c3 = wave_sum_i(c3);
    if (lane == 0) {
      const float invZ = 1.0f / Z;
      const float p0 = expf(sp0 * INV_TEMP - m) * invZ;
      const float p1 = expf(sp1 * INV_TEMP - m) * invZ;
      const float p2 = expf(sp2 * INV_TEMP - m) * invZ;
      const float p3 = expf(sp3 * INV_TEMP - m) * invZ;
      const float err = p0 / (float)(c0 + 1) + p1 / (float)(c1 + 1) +
                        p2 / (float)(c2 + 1) + p3 / (float)(c3 + 1);
      partials[b] = err;                           // expected RR for this row
      partials[B_DIM + b] = sp0 + sp1 + sp2 + sp3; // sum of pos sims
    }
  }
}

__global__ __launch_bounds__(256) void rr_finalize_kernel(
    const float* __restrict__ partials, float* __restrict__ out) {
  const int t = threadIdx.x;
  const int lane = t & 63;
  const int wave = t >> 6;
  float rr = partials[t];
  float ps = partials[B_DIM + t];
  rr = wave_sum_f(rr);
  ps = wave_sum_f(ps);
  __shared__ float srr[4], sps[4];
  if (lane == 0) { srr[wave] = rr; sps[wave] = ps; }
  __syncthreads();
  if (t == 0) {
    const float SRR = srr[0] + srr[1] + srr[2] + srr[3];
    const float SPS = sps[0] + sps[1] + sps[2] + sps[3];
    const float loss =
        -(SRR / (float)B_DIM) +
        POS_W * (1.0f - SPS / (float)(B_DIM * P_DIM));
    out[0] = loss;
  }
}

extern "C" void kernel_launch(void* const* d_in, const int* in_sizes, int n_in,
                              void* d_out, int out_size, void* d_ws, size_t ws_size,
                              hipStream_t stream) {
  const float* anchor = (const float*)d_in[0];
  const float* positives = (const float*)d_in[1];
  const float* negatives = (const float*)d_in[2];
  float* partials = (float*)d_ws;  // 2*B_DIM floats, fully overwritten each launch
  float* out = (float*)d_out;

  rr_row_kernel<<<B_DIM, 1024, 0, stream>>>(anchor, positives, negatives, partials);
  rr_finalize_kernel<<<1, 256, 0, stream>>>(partials, out);
}

// Round 3
// 676.095 us; speedup vs baseline: 1.0310x; 1.0043x over previous
//
#include <hip/hip_runtime.h>
#include <math.h>

#define B_DIM 256
#define P_DIM 4
#define N_DIM 1024
#define D_DIM 512
#define NV (P_DIM + N_DIM)   // 1028 sims per row; 8 iters * 16 waves * 8 = 1024, +4 tail
#define INV_TEMP 10.0f       // 1 / 0.1
#define POS_W 0.3f
#define EPS_C 1e-8f

__device__ __forceinline__ float wave_sum_f(float v) {
#pragma unroll
  for (int m = 1; m < 64; m <<= 1) v += __shfl_xor(v, m, 64);
  return v;
}

__device__ __forceinline__ float wave_max_f(float v) {
#pragma unroll
  for (int m = 1; m < 64; m <<= 1) v = fmaxf(v, __shfl_xor(v, m, 64));
  return v;
}

__device__ __forceinline__ int wave_sum_i(int v) {
#pragma unroll
  for (int m = 1; m < 64; m <<= 1) v += __shfl_xor(v, m, 64);
  return v;
}

__device__ __forceinline__ float dot4(float4 a, float4 b) {
  return a.x * b.x + a.y * b.y + a.z * b.z + a.w * b.w;
}

// One block per batch row, 1024 threads = 16 waves/CU.
// Phase 1: 1028 cosine sims -> LDS, 8 vectors per wave-iteration
//          (16 outstanding float4 loads/lane; guard-free for 1024 vectors,
//           wave 0 handles the 4-vector tail).
// Phase 2 (wave 0): softmax + stable-rank count — a few µs, negligible.
__global__ __launch_bounds__(1024) void rr_row_kernel(
    const float* __restrict__ anchor, const float* __restrict__ positives,
    const float* __restrict__ negatives, float* __restrict__ partials) {
  const int b = blockIdx.x;
  const int lane = threadIdx.x & 63;
  const int wave = threadIdx.x >> 6;

  __shared__ float sims[NV];

  const float4* arow = (const float4*)(anchor + (size_t)b * D_DIM);
  const float4 a0 = arow[lane];
  const float4 a1 = arow[lane + 64];
  float asq = dot4(a0, a0) + dot4(a1, a1);
  asq = wave_sum_f(asq);
  const float anorm = sqrtf(asq);

  const float* posrow = positives + (size_t)b * P_DIM * D_DIM;
  const float* negrow = negatives + (size_t)b * N_DIM * D_DIM;

  // Main loop: vectors [0, 1024), guard-free. 8 consecutive vectors per wave.
#pragma unroll 1
  for (int it = 0; it < 8; ++it) {
    const int v0 = it * 128 + wave * 8;
    float4 bv[8][2];
#pragma unroll
    for (int i = 0; i < 8; ++i) {
      const int v = v0 + i;
      const float* src = (v < P_DIM) ? (posrow + (size_t)v * D_DIM)
                                     : (negrow + (size_t)(v - P_DIM) * D_DIM);
      const float4* p = (const float4*)src;
      bv[i][0] = p[lane];
      bv[i][1] = p[lane + 64];
    }
    float d[8], bq[8];
#pragma unroll
    for (int i = 0; i < 8; ++i) {
      d[i]  = dot4(a0, bv[i][0]) + dot4(a1, bv[i][1]);
      bq[i] = dot4(bv[i][0], bv[i][0]) + dot4(bv[i][1], bv[i][1]);
    }
#pragma unroll
    for (int i = 0; i < 8; ++i) {
      d[i]  = wave_sum_f(d[i]);
      bq[i] = wave_sum_f(bq[i]);
    }
    if (lane == 0) {
#pragma unroll
      for (int i = 0; i < 8; ++i) {
        const float den = fmaxf(anorm * sqrtf(bq[i]), EPS_C);
        sims[v0 + i] = d[i] / den;
      }
    }
  }

  // Tail: vectors 1024..1027 (all negatives), wave 0 only.
  if (wave == 0) {
#pragma unroll
    for (int i = 0; i < 4; ++i) {
      const int v = 1024 + i;
      const float4* p = (const float4*)(negrow + (size_t)(v - P_DIM) * D_DIM);
      const float4 b0 = p[lane];
      const float4 b1 = p[lane + 64];
      float d  = dot4(a0, b0) + dot4(a1, b1);
      float bq = dot4(b0, b0) + dot4(b1, b1);
      d  = wave_sum_f(d);
      bq = wave_sum_f(bq);
      if (lane == 0) {
        const float den = fmaxf(anorm * sqrtf(bq), EPS_C);
        sims[v] = d / den;
      }
    }
  }
  __syncthreads();

  if (wave == 0) {
    float m = -3.4e38f;
    for (int v = lane; v < NV; v += 64) m = fmaxf(m, sims[v] * INV_TEMP);
    m = wave_max_f(m);
    float Z = 0.0f;
    for (int v = lane; v < NV; v += 64) Z += expf(sims[v] * INV_TEMP - m);
    Z = wave_sum_f(Z);
    // stable-argsort rank: rank_k = #{i: s_i > s_k} + #{i < k: s_i == s_k}
    const float sp0 = sims[0], sp1 = sims[1], sp2 = sims[2], sp3 = sims[3];
    int c0 = 0, c1 = 0, c2 = 0, c3 = 0;
    for (int v = lane; v < NV; v += 64) {
      const float s = sims[v];
      c0 += (s > sp0);
      c1 += (s > sp1) || (s == sp1 && v < 1);
      c2 += (s > sp2) || (s == sp2 && v < 2);
      c3 += (s > sp3) || (s == sp3 && v < 3);
    }
    c0 = wave_sum_i(c0);
    c1 = wave_sum_i(c1);
    c2 = wave_sum_i(c2);
    c3 = wave_sum_i(c3);
    if (lane == 0) {
      const float invZ = 1.0f / Z;
      const float p0 = expf(sp0 * INV_TEMP - m) * invZ;
      const float p1 = expf(sp1 * INV_TEMP - m) * invZ;
      const float p2 = expf(sp2 * INV_TEMP - m) * invZ;
      const float p3 = expf(sp3 * INV_TEMP - m) * invZ;
      const float err = p0 / (float)(c0 + 1) + p1 / (float)(c1 + 1) +
                        p2 / (float)(c2 + 1) + p3 / (float)(c3 + 1);
      partials[b] = err;
      partials[B_DIM + b] = sp0 + sp1 + sp2 + sp3;
    }
  }
}

__global__ __launch_bounds__(256) void rr_finalize_kernel(
    const float* __restrict__ partials, float* __restrict__ out) {
  const int t = threadIdx.x;
  const int lane = t & 63;
  const int wave = t >> 6;
  float rr = partials[t];
  float ps = partials[B_DIM + t];
  rr = wave_sum_f(rr);
  ps = wave_sum_f(ps);
  __shared__ float srr[4], sps[4];
  if (lane == 0) { srr[wave] = rr; sps[wave] = ps; }
  __syncthreads();
  if (t == 0) {
    const float SRR = srr[0] + srr[1] + srr[2] + srr[3];
    const float SPS = sps[0] + sps[1] + sps[2] + sps[3];
    const float loss =
        -(SRR / (float)B_DIM) +
        POS_W * (1.0f - SPS / (float)(B_DIM * P_DIM));
    out[0] = loss;
  }
}

extern "C" void kernel_launch(void* const* d_in, const int* in_sizes, int n_in,
                              void* d_out, int out_size, void* d_ws, size_t ws_size,
                              hipStream_t stream) {
  const float* anchor = (const float*)d_in[0];
  const float* positives = (const float*)d_in[1];
  const float* negatives = (const float*)d_in[2];
  float* partials = (float*)d_ws;
  float* out = (float*)d_out;

  rr_row_kernel<<<B_DIM, 1024, 0, stream>>>(anchor, positives, negatives, partials);
  rr_finalize_kernel<<<1, 256, 0, stream>>>(partials, out);
}